// Round 5
// baseline (131.817 us; speedup 1.0000x reference)
//
#include <hip/hip_runtime.h>
#include <math.h>

#define B_    8
#define S_    128
#define K_    12
#define DAR_  256
#define DENC_ 256
#define NNEG_ 128
#define W_    116          // S - K
#define BW_   928          // B * W
#define HBW_  464          // BW / 2

typedef __attribute__((ext_vector_type(8))) short short8;   // 8 bf16 (4 VGPRs)
typedef __attribute__((ext_vector_type(4))) float floatx4;  // MFMA C/D

static __device__ __forceinline__ unsigned short f2bf(float f) {
    union { float f; unsigned int u; } v; v.f = f;
    return (unsigned short)((v.u + 0x7FFFu + ((v.u >> 16) & 1u)) >> 16);  // RNE
}

static __device__ __forceinline__ uint4 pack8(const float* p) {
    float4 v0 = *(const float4*)p;
    float4 v1 = *(const float4*)(p + 4);
    uint4 o;
    o.x = f2bf(v0.x) | ((unsigned)f2bf(v0.y) << 16);
    o.y = f2bf(v0.z) | ((unsigned)f2bf(v0.w) << 16);
    o.z = f2bf(v1.x) | ((unsigned)f2bf(v1.y) << 16);
    o.w = f2bf(v1.z) | ((unsigned)f2bf(v1.w) << 16);
    return o;
}

// ---------------------------------------------------------------------------
// Stage 1 (MFMA, fp32 inputs packed in-register): locC[k][bw][e] bf16.
// Grid (16,4,12): x<15 compute (64x64 tile); x==15 -> 48 blocks cast enc->bf16.
// ---------------------------------------------------------------------------
__global__ __launch_bounds__(256) void stage1_mfma(
    const float* __restrict__ cFeat,   // (B,S,256) fp32
    const float* __restrict__ Wp,      // (K,256,256) fp32
    const float* __restrict__ enc,     // (B,S,256) fp32
    unsigned short* __restrict__ ench, // (B,S,256) bf16 out
    unsigned short* __restrict__ locCh)// (K,BW,256) bf16 out
{
    const int tid = threadIdx.x;

    if (blockIdx.x == 15) {            // ---- enc cast: 48 blocks ----
        const int cb = blockIdx.z * 4 + blockIdx.y;       // 0..47
#pragma unroll
        for (int i = 0; i < 3; ++i) {
            const int c = cb * 768 + i * 256 + tid;       // 8-float chunks
            if (c < 32768)
                *(uint4*)(ench + c * 8) = pack8(enc + c * 8);
        }
        return;
    }

    __shared__ unsigned short Bh[64 * 256];   // 32 KB, swizzled

    const int mt = blockIdx.x;                // 0..14 bw-tiles (last partial)
    const int nt = blockIdx.y;                // 4 e-tiles
    const int k  = blockIdx.z;                // 12

    const int lane = tid & 63, wv = tid >> 6;
    const int l15 = lane & 15, quad = lane >> 4;

    // ---- A fragments direct from global fp32, packed to bf16 ----
    const int am = mt * 64 + wv * 16 + l15;   // bw row
    short8 a[8];
    if (am < BW_) {
        const int b = am / W_, w = am - b * W_;
        const float* arow = cFeat + (size_t)(b * S_ + w) * 256;
#pragma unroll
        for (int kt = 0; kt < 8; ++kt) {
            uint4 p = pack8(arow + kt * 32 + quad * 8);
            a[kt] = *(short8*)&p;
        }
    } else {
#pragma unroll
        for (int kt = 0; kt < 8; ++kt) a[kt] = short8{0,0,0,0,0,0,0,0};
    }

    // ---- B staging: 64 rows x 32 chunks, fp32->bf16, swizzled ----
#pragma unroll
    for (int i = 0; i < 8; ++i) {
        const int flat = i * 256 + tid;
        const int row = flat >> 5, ch = flat & 31;
        const int e = nt * 64 + row;
        uint4 bv = pack8(Wp + ((size_t)(k * 256 + e) * 256 + ch * 8));
        *(uint4*)&Bh[(row * 32 + (ch ^ (row & 7))) * 8] = bv;
    }
    __syncthreads();

    floatx4 acc[4];
#pragma unroll
    for (int n4 = 0; n4 < 4; ++n4) {
        floatx4 c = {0.f, 0.f, 0.f, 0.f};
        const int bn = n4 * 16 + l15;
#pragma unroll
        for (int kt = 0; kt < 8; ++kt) {
            const int ch = kt * 4 + quad;
            short8 bfrag = *(const short8*)&Bh[(bn * 32 + (ch ^ (bn & 7))) * 8];
            c = __builtin_amdgcn_mfma_f32_16x16x32_bf16(a[kt], bfrag, c, 0, 0, 0);
        }
        acc[n4] = c;
    }

    // D: col(e)=l15, row(bw)=quad*4+r within subtile
#pragma unroll
    for (int n4 = 0; n4 < 4; ++n4) {
        const int e = nt * 64 + n4 * 16 + l15;
#pragma unroll
        for (int r = 0; r < 4; ++r) {
            const int bwo = mt * 64 + wv * 16 + quad * 4 + r;
            if (bwo < BW_)
                locCh[((size_t)k * BW_ + bwo) * 256 + e] = f2bf(acc[n4][r]);
        }
    }
}

// ---------------------------------------------------------------------------
// Stage 2 (MFMA): block handles TWO (b,w) pairs (bw, bw+464) for 2x
// memory-level parallelism. Fragments direct from global; LDS = indices +
// logit tables only (~14 KB).
// ---------------------------------------------------------------------------
__global__ __launch_bounds__(256) void stage2_mfma(
    const unsigned short* __restrict__ ench,   // (B,S,256) bf16
    const unsigned short* __restrict__ locCh,  // (K,BW,256) bf16
    const int* __restrict__ batchIdx,
    const int* __restrict__ seqIdx,
    float* __restrict__ part)                  // (2K, BW)
{
    __shared__ int   idxL[2][144];
    __shared__ float sc[2][K_ * 132];   // [0..127]=neg, [128]=pos

    const int tid = threadIdx.x;
    const int lane = tid & 63, wv = tid >> 6;
    const int l15 = lane & 15, quad = lane >> 4;

    int bwp[2], bp[2], wp[2];
#pragma unroll
    for (int pr = 0; pr < 2; ++pr) {
        bwp[pr] = blockIdx.x + pr * HBW_;
        bp[pr] = bwp[pr] / W_;
        wp[pr] = bwp[pr] - bp[pr] * W_;
    }

    // ---- indices: threads 0..127 -> pair0 negs, 128..255 -> pair1 negs ----
    {
        const int pr = tid >> 7, n = tid & 127;
        const int ii = (bp[pr] * NNEG_ + n) * W_ + wp[pr];
        const int bi = batchIdx[ii];
        int si = seqIdx[ii] + wp[pr];          // seqIdx in [1,S), w<=115 -> <243
        if (si >= S_) si -= S_;
        idxL[pr][n] = bi * S_ + si;
    }
    if (tid < 24) {                            // positives
        const int pr = tid / K_, kk = tid - pr * K_;
        idxL[pr][128 + kk] = bp[pr] * S_ + wp[pr] + 1 + kk;
    }

    // ---- A fragments (both pairs) direct from global ----
    const int m = (l15 < K_) ? l15 : (K_ - 1);
    short8 a[2][8];
#pragma unroll
    for (int pr = 0; pr < 2; ++pr) {
        const unsigned short* arow = locCh + ((size_t)m * BW_ + bwp[pr]) * 256;
#pragma unroll
        for (int kt = 0; kt < 8; ++kt)
            a[pr][kt] = *(const short8*)(arow + kt * 32 + quad * 8);
    }
    __syncthreads();

    // ---- 9 N-tiles over 4 waves, both pairs interleaved ----
    floatx4 accT[2][3];
#pragma unroll
    for (int u = 0; u < 3; ++u) {
        const int t = wv + u * 4;
#pragma unroll
        for (int pr = 0; pr < 2; ++pr) {
            floatx4 c = {0.f, 0.f, 0.f, 0.f};
            if (t < 9) {
                const int n = t * 16 + l15;
                const int nn = (n < 140) ? n : 128;
                const unsigned short* brow = ench + (size_t)idxL[pr][nn] * 256;
#pragma unroll
                for (int kt = 0; kt < 8; ++kt) {
                    short8 bfrag = *(const short8*)(brow + kt * 32 + quad * 8);
                    c = __builtin_amdgcn_mfma_f32_16x16x32_bf16(a[pr][kt], bfrag, c, 0, 0, 0);
                }
            }
            accT[pr][u] = c;
        }
    }

    const float inv = 1.0f / 256.0f;
#pragma unroll
    for (int u = 0; u < 3; ++u) {
        const int t = wv + u * 4;
        if (t < 9) {
#pragma unroll
            for (int pr = 0; pr < 2; ++pr) {
#pragma unroll
                for (int r = 0; r < 4; ++r) {
                    const int mm = quad * 4 + r;       // accumulator row = k
                    if (mm < K_) {
                        const float val = accT[pr][u][r] * inv;
                        if (t < 8)           sc[pr][mm * 132 + t * 16 + l15] = val;
                        else if (l15 == mm)  sc[pr][mm * 132 + 128] = val;
                    }
                }
            }
        }
    }
    __syncthreads();

    // ---- LSE + acc per k, both pairs (wave wv: k = wv, wv+4, wv+8) ----
    for (int k = wv; k < K_; k += 4) {
#pragma unroll
        for (int pr = 0; pr < 2; ++pr) {
            const float x0  = sc[pr][k * 132 + lane];
            const float x1  = sc[pr][k * 132 + 64 + lane];
            const float pos = sc[pr][k * 132 + 128];
            float mn = fmaxf(x0, x1);
#pragma unroll
            for (int o = 1; o < 64; o <<= 1) mn = fmaxf(mn, __shfl_xor(mn, o, 64));
            const float m2 = fmaxf(mn, pos);
            float s = __expf(x0 - m2) + __expf(x1 - m2);
#pragma unroll
            for (int o = 1; o < 64; o <<= 1) s += __shfl_xor(s, o, 64);
            if (lane == 0) {
                const float lse = m2 + __logf(s + __expf(pos - m2));
                part[k * BW_ + bwp[pr]]        = lse - pos;
                part[(K_ + k) * BW_ + bwp[pr]] = (pos >= mn) ? 1.0f : 0.0f;
            }
        }
    }
}

// ---------------------------------------------------------------------------
// Stage 3: reduce (2K, BW) partials to the 24 outputs.
// ---------------------------------------------------------------------------
__global__ __launch_bounds__(256) void stage3_reduce(
    const float* __restrict__ part, float* __restrict__ out)
{
    __shared__ float wsum[4];
    const int o = blockIdx.x, tid = threadIdx.x;
    float s = 0.f;
    for (int i = tid; i < BW_; i += 256) s += part[o * BW_ + i];
#pragma unroll
    for (int off = 1; off < 64; off <<= 1) s += __shfl_xor(s, off, 64);
    if ((tid & 63) == 0) wsum[tid >> 6] = s;
    __syncthreads();
    if (tid == 0)
        out[o] = (wsum[0] + wsum[1] + wsum[2] + wsum[3]) / (float)BW_;
}

// ---------------------------------------------------------------------------
extern "C" void kernel_launch(void* const* d_in, const int* in_sizes, int n_in,
                              void* d_out, int out_size, void* d_ws, size_t ws_size,
                              hipStream_t stream) {
    const float* cFeat    = (const float*)d_in[0];
    const float* enc      = (const float*)d_in[1];
    const float* Wp       = (const float*)d_in[2];
    const int*   batchIdx = (const int*)d_in[3];
    const int*   seqIdx   = (const int*)d_in[4];
    float* out = (float*)d_out;

    unsigned short* ench  = (unsigned short*)d_ws;            // 262144 bf16
    unsigned short* locCh = ench + 262144;                    // K*BW*256 bf16
    float* part  = (float*)(locCh + (size_t)K_ * BW_ * 256);  // (2K,BW)
    float* part2 = part  + 2 * K_ * BW_;                      // measurement dup
    float* part3 = part2 + 2 * K_ * BW_;                      // measurement dup

    hipLaunchKernelGGL(stage1_mfma, dim3(16, 4, 12), dim3(256), 0, stream,
                       cFeat, Wp, enc, ench, locCh);
    // Real pass + two duplicate passes (deterministic, same work every call).
    // Purpose: round-6 will drop the dups; delta = 2 x stage2 duration, which
    // splits the unexplained ~44 us between stage1 and stage2 exactly.
    hipLaunchKernelGGL(stage2_mfma, dim3(HBW_), dim3(256), 0, stream,
                       ench, locCh, batchIdx, seqIdx, part);
    hipLaunchKernelGGL(stage2_mfma, dim3(HBW_), dim3(256), 0, stream,
                       ench, locCh, batchIdx, seqIdx, part2);
    hipLaunchKernelGGL(stage2_mfma, dim3(HBW_), dim3(256), 0, stream,
                       ench, locCh, batchIdx, seqIdx, part3);
    hipLaunchKernelGGL(stage3_reduce, dim3(24), dim3(256), 0, stream,
                       part, out);
}